// Round 1
// baseline (4270.652 us; speedup 1.0000x reference)
//
#include <hip/hip_runtime.h>
#include <math.h>

#define D 128
#define P 8192
#define PU 8234
#define NHE 51
#define NUC 42

__device__ inline void atomAddF(float* p, float v) {
#if defined(__HIP_PLATFORM_AMD__)
    unsafeAtomicAdd(p, v);
#else
    atomicAdd(p, v);
#endif
}

// ---------------- tables: Cm[k*128+t]=cos(2*pi*k*t/128), Sm = -sin ----------------
__global__ void k_tables(float* Cm, float* Sm) {
    int idx = blockIdx.x * 256 + threadIdx.x;
    if (idx >= D * D) return;
    int k = idx >> 7, t = idx & 127;
    int m = (k * t) & 127;
    float ang = (float)m * 0.049087385212340517f; // 2*pi/128
    Cm[idx] = cosf(ang);
    Sm[idx] = -sinf(ang);
}

// ---------------- reshape cheby coeffs (i,o,k) -> W[(i*4+k)*128+o] ----------------
__global__ void k_reshape(const float* __restrict__ cr, const float* __restrict__ ci,
                          float* __restrict__ Wr, float* __restrict__ Wi) {
    int idx = blockIdx.x * 256 + threadIdx.x;
    if (idx >= 512 * D) return;
    int o = idx & 127;
    int ik = idx >> 7;
    int i = ik >> 2, kk = ik & 3;
    Wr[idx] = cr[(i * 128 + o) * 4 + kk];
    Wi[idx] = ci[(i * 128 + o) * 4 + kk];
}

// ---------------- generic GEMM: C[M x 128] += alpha * A[M x K] @ B[K x 128] ----------------
// grid (ceil(M/64), ksplit), block 256. C must be zeroed before. atomicAdd store.
#define GEMM_BODY(K_)                                                     \
    {                                                                     \
        float a[4], b[8];                                                 \
        _Pragma("unroll") for (int r = 0; r < 4; r++) a[r] = As[ty + 16 * r][K_]; \
        _Pragma("unroll") for (int c = 0; c < 8; c++) b[c] = Bs[K_][tx + 16 * c]; \
        _Pragma("unroll") for (int r = 0; r < 4; r++)                     \
            _Pragma("unroll") for (int c = 0; c < 8; c++)                 \
                acc[r][c] += a[r] * b[c];                                 \
    }

__global__ __launch_bounds__(256) void k_gemm(const float* __restrict__ A, int lda,
                                              const float* __restrict__ B,
                                              float* __restrict__ C,
                                              int M, int K, float alpha, int klen) {
    __shared__ float As[64][33];
    __shared__ float Bs[32][128];
    const int t = threadIdx.x;
    const int tx = t & 15, ty = t >> 4;
    const int i0 = blockIdx.x * 64;
    const int kbeg = blockIdx.y * klen;
    const int kend = min(K, kbeg + klen);
    float acc[4][8];
#pragma unroll
    for (int r = 0; r < 4; r++)
#pragma unroll
        for (int c = 0; c < 8; c++) acc[r][c] = 0.f;

    for (int k0 = kbeg; k0 < kend; k0 += 32) {
        // stage A 64x32 (scalar loads: lda may be odd)
#pragma unroll
        for (int q = 0; q < 2; q++) {
            int idx = t + q * 256;
            int row = idx >> 3;
            int col = (idx & 7) * 4;
            int gi = i0 + row;
#pragma unroll
            for (int u = 0; u < 4; u++) {
                int gk = k0 + col + u;
                As[row][col + u] = (gi < M && gk < kend) ? A[(size_t)gi * lda + gk] : 0.f;
            }
        }
        // stage B 32x128 (float4, B row stride is 128)
#pragma unroll
        for (int q = 0; q < 4; q++) {
            int idx = t + q * 256;
            int row = idx >> 5;
            int col4 = (idx & 31) * 4;
            int gk = k0 + row;
            float4 v = make_float4(0.f, 0.f, 0.f, 0.f);
            if (gk < kend) v = *reinterpret_cast<const float4*>(B + (size_t)gk * 128 + col4);
            *reinterpret_cast<float4*>(&Bs[row][col4]) = v;
        }
        __syncthreads();
        int klim = min(32, kend - k0);
        if (klim == 32) {
#pragma unroll
            for (int k = 0; k < 32; k++) GEMM_BODY(k)
        } else {
            for (int k = 0; k < klim; k++) GEMM_BODY(k)
        }
        __syncthreads();
    }
#pragma unroll
    for (int r = 0; r < 4; r++) {
        int gi = i0 + ty + 16 * r;
        if (gi < M) {
#pragma unroll
            for (int c = 0; c < 8; c++)
                atomAddF(&C[(size_t)gi * 128 + tx + 16 * c], alpha * acc[r][c]);
        }
    }
}

// ---------------- T[i,:] += HG_pu[i,:] @ X  (i < NHE). grid (NHE, chunks) ----------------
__global__ void k_small_pu(const float* __restrict__ PUm, const float* __restrict__ X,
                           float* __restrict__ T, int Kn) {
    int i = blockIdx.x;
    int klen = (Kn + gridDim.y - 1) / gridDim.y;
    int kbeg = blockIdx.y * klen;
    int kend = min(Kn, kbeg + klen);
    int t = threadIdx.x;
    int d = t & 127, half = t >> 7;
    float acc = 0.f;
    for (int k = kbeg + half; k < kend; k += 2)
        acc += PUm[(size_t)i * Kn + k] * X[(size_t)k * 128 + d];
    atomAddF(&T[i * 128 + d], acc);
}

// ---------------- gate epilogue: out = X * sigmoid(pre + bias) ----------------
__global__ void k_gate_ep(const float* __restrict__ X, const float* __restrict__ pre,
                          const float* __restrict__ bias, float* __restrict__ out, int n) {
    int idx = blockIdx.x * 256 + threadIdx.x;
    if (idx < n) {
        float s = pre[idx] + bias[idx & 127];
        s = 1.f / (1.f + expf(-s));
        out[idx] = X[idx] * s;
    }
}

__global__ void k_add(const float* __restrict__ a, const float* __restrict__ b,
                      float* __restrict__ out, int n) {
    int idx = blockIdx.x * 256 + threadIdx.x;
    if (idx < n) out[idx] = a[idx] + b[idx];
}

// ---------------- out = l2norm((a+b+c)/3) per row. grid nrows, block 128 ----------------
__global__ void k_acc3norm(const float* __restrict__ a, const float* __restrict__ b,
                           const float* __restrict__ c, float* __restrict__ out) {
    __shared__ float red[128];
    size_t i = blockIdx.x;
    int d = threadIdx.x;
    float v = (a[i * 128 + d] + b[i * 128 + d] + c[i * 128 + d]) * (1.f / 3.f);
    red[d] = v * v;
    __syncthreads();
    for (int s = 64; s > 0; s >>= 1) {
        if (d < s) red[d] += red[d + s];
        __syncthreads();
    }
    float inv = 1.f / fmaxf(sqrtf(red[0]), 1e-12f);
    out[i * 128 + d] = v * inv;
}

// ---------------- inv[i] = 1/max(||X[i,:]||, 1e-12). grid nrows, block 128 ----------------
__global__ void k_invnorm(const float* __restrict__ X, float* __restrict__ inv) {
    __shared__ float red[128];
    size_t i = blockIdx.x;
    int d = threadIdx.x;
    float v = X[i * 128 + d];
    red[d] = v * v;
    __syncthreads();
    for (int s = 64; s > 0; s >>= 1) {
        if (d < s) red[d] += red[d + s];
        __syncthreads();
    }
    if (d == 0) inv[i] = 1.f / fmaxf(sqrtf(red[0]), 1e-12f);
}

// ---------------- fused InfoNCE tile pass ----------------
// sim[i,j] = 5 * inv1[i]*inv2[j] * dot(Z1[i],Z2[j]); accumulates exp row sums, col
// sums, and diag sum. grid (ceil(n1/128), ceil(n2/128)), block 256, 8x8 micro-tile.
__global__ __launch_bounds__(256) void k_rowcol(
    const float* __restrict__ Z1, const float* __restrict__ inv1, int n1,
    const float* __restrict__ Z2, const float* __restrict__ inv2, int n2,
    float* __restrict__ rowsum, float* __restrict__ colsum, float* __restrict__ diagsum) {
    __shared__ float As[128][33];
    __shared__ float Bs[128][33];
    __shared__ float dred[256];
    const int t = threadIdx.x;
    const int tx = t & 15, ty = t >> 4;
    const int i0 = blockIdx.x * 128, j0 = blockIdx.y * 128;
    float acc[8][8];
#pragma unroll
    for (int r = 0; r < 8; r++)
#pragma unroll
        for (int c = 0; c < 8; c++) acc[r][c] = 0.f;

    for (int kc = 0; kc < 128; kc += 32) {
#pragma unroll
        for (int q = 0; q < 4; q++) {
            int idx = t + q * 256;
            int row = idx >> 3;
            int col = (idx & 7) * 4;
            int gi = i0 + row;
            float4 v = make_float4(0.f, 0.f, 0.f, 0.f);
            float sc = 0.f;
            if (gi < n1) {
                v = *reinterpret_cast<const float4*>(Z1 + (size_t)gi * 128 + kc + col);
                sc = inv1[gi] * 5.0f;
            }
            As[row][col + 0] = v.x * sc;
            As[row][col + 1] = v.y * sc;
            As[row][col + 2] = v.z * sc;
            As[row][col + 3] = v.w * sc;
            int gj = j0 + row;
            float4 w = make_float4(0.f, 0.f, 0.f, 0.f);
            float sc2 = 0.f;
            if (gj < n2) {
                w = *reinterpret_cast<const float4*>(Z2 + (size_t)gj * 128 + kc + col);
                sc2 = inv2[gj];
            }
            Bs[row][col + 0] = w.x * sc2;
            Bs[row][col + 1] = w.y * sc2;
            Bs[row][col + 2] = w.z * sc2;
            Bs[row][col + 3] = w.w * sc2;
        }
        __syncthreads();
#pragma unroll
        for (int k = 0; k < 32; k++) {
            float a[8], b[8];
#pragma unroll
            for (int r = 0; r < 8; r++) a[r] = As[ty + 16 * r][k];
#pragma unroll
            for (int c = 0; c < 8; c++) b[c] = Bs[tx + 16 * c][k];
#pragma unroll
            for (int r = 0; r < 8; r++)
#pragma unroll
                for (int c = 0; c < 8; c++) acc[r][c] += a[r] * b[c];
        }
        __syncthreads();
    }
    // epilogue: exp, mask, per-thread row/col partials
    float rs[8], cs[8];
#pragma unroll
    for (int r = 0; r < 8; r++) rs[r] = 0.f;
#pragma unroll
    for (int c = 0; c < 8; c++) cs[c] = 0.f;
    float dsum = 0.f;
#pragma unroll
    for (int r = 0; r < 8; r++) {
        int gi = i0 + ty + 16 * r;
#pragma unroll
        for (int c = 0; c < 8; c++) {
            int gj = j0 + tx + 16 * c;
            bool valid = (gi < n1) && (gj < n2);
            float e = valid ? __expf(acc[r][c]) : 0.f;
            rs[r] += e;
            cs[c] += e;
            if (valid && gi == gj) dsum += acc[r][c];
        }
    }
#pragma unroll
    for (int r = 0; r < 8; r++) As[ty + 16 * r][tx] = rs[r];
#pragma unroll
    for (int c = 0; c < 8; c++) Bs[tx + 16 * c][ty] = cs[c];
    dred[t] = dsum;
    __syncthreads();
    if (t < 128) {
        float s = 0.f;
#pragma unroll
        for (int u = 0; u < 16; u++) s += As[t][u];
        if (i0 + t < n1) atomAddF(&rowsum[i0 + t], s);
        float s2 = 0.f;
#pragma unroll
        for (int u = 0; u < 16; u++) s2 += Bs[t][u];
        if (j0 + t < n2) atomAddF(&colsum[j0 + t], s2);
    }
    __syncthreads();
    for (int s = 128; s > 0; s >>= 1) {
        if (t < s) dred[t] += dred[t + s];
        __syncthreads();
    }
    if (t == 0 && dred[0] != 0.f) atomAddF(diagsum, dred[0]);
}

// ---------------- reduce InfoNCE: loss += 0.5*mean(log rs + log cs) - diag/n ----------------
__global__ void k_nce_reduce(const float* __restrict__ rs, const float* __restrict__ cs,
                             const float* __restrict__ diag, int n, float* __restrict__ loss) {
    __shared__ float red[256];
    int t = threadIdx.x;
    float s = 0.f;
    for (int i = blockIdx.x * 256 + t; i < n; i += gridDim.x * 256)
        s += logf(rs[i]) + logf(cs[i]);
    red[t] = s;
    __syncthreads();
    for (int st = 128; st > 0; st >>= 1) {
        if (t < st) red[t] += red[t + st];
        __syncthreads();
    }
    if (t == 0) {
        float v = 0.5f * red[0] / (float)n;
        if (blockIdx.x == 0) v -= diag[0] / (float)n;
        atomAddF(loss, v);
    }
}

// ---------------- small InfoNCE (42x42), single block ----------------
__global__ void k_ssl(const float* __restrict__ UE, const float* __restrict__ HGU,
                      float* __restrict__ loss) {
    __shared__ float A[NUC][128], B[NUC][128];
    __shared__ float sim[NUC][NUC];
    __shared__ float invA[NUC], invB[NUC];
    __shared__ float pr[64];
    int t = threadIdx.x;
    for (int idx = t; idx < NUC * 128; idx += 256) {
        A[idx >> 7][idx & 127] = UE[idx];
        B[idx >> 7][idx & 127] = HGU[9 * 128 + idx];
    }
    __syncthreads();
    if (t < 2 * NUC) {
        int i = (t < NUC) ? t : t - NUC;
        float s = 0.f;
        if (t < NUC) {
            for (int d = 0; d < 128; d++) { float v = A[i][d]; s += v * v; }
            invA[i] = 1.f / fmaxf(sqrtf(s), 1e-12f);
        } else {
            for (int d = 0; d < 128; d++) { float v = B[i][d]; s += v * v; }
            invB[i] = 1.f / fmaxf(sqrtf(s), 1e-12f);
        }
    }
    __syncthreads();
    for (int idx = t; idx < NUC * NUC; idx += 256) {
        int i = idx / NUC, j = idx % NUC;
        float s = 0.f;
        for (int d = 0; d < 128; d++) s += A[i][d] * B[j][d];
        sim[i][j] = s * invA[i] * invB[j] * 5.0f;
    }
    __syncthreads();
    float part = 0.f;
    if (t < NUC) {
        float rsu = 0.f, csu = 0.f;
        for (int j = 0; j < NUC; j++) {
            rsu += __expf(sim[t][j]);
            csu += __expf(sim[j][t]);
        }
        part = 0.5f * (logf(rsu) + logf(csu)) - sim[t][t];
    }
    if (t < 64) pr[t] = (t < NUC) ? part : 0.f;
    __syncthreads();
    if (t == 0) {
        float s = 0.f;
        for (int i = 0; i < NUC; i++) s += pr[i];
        atomAddF(loss, s / (float)NUC);
    }
}

// ---------------- cheby features: G[n*512 + 4i + k] = T_k(tanh xa) + T_k(tanh xb) ----------------
__global__ void k_features(const float* __restrict__ Xa, const float* __restrict__ Xb,
                           float* __restrict__ G, int n) {
    int idx = blockIdx.x * 256 + threadIdx.x;
    if (idx < n) {
        float x1 = tanhf(Xa[idx]), x2 = tanhf(Xb[idx]);
        float4 w;
        w.x = 2.0f;
        w.y = x1 + x2;
        w.z = (2.f * x1 * x1 - 1.f) + (2.f * x2 * x2 - 1.f);
        w.w = x1 * (4.f * x1 * x1 - 3.f) + x2 * (4.f * x2 * x2 - 3.f);
        *reinterpret_cast<float4*>(G + (size_t)idx * 4) = w;
    }
}

// ---------------- mix: a = sig(pre)*a + (1-sig)*b ----------------
__global__ void k_mix(const float* __restrict__ pre, float* __restrict__ a,
                      const float* __restrict__ b, int n) {
    int idx = blockIdx.x * 256 + threadIdx.x;
    if (idx < n) {
        float g = 1.f / (1.f + expf(-pre[idx]));
        a[idx] = g * a[idx] + (1.f - g) * b[idx];
    }
}

// ---------------- final_u[d] = UE[ui][d] + HGU[ucol][d] ----------------
__global__ void k_finalu(const float* __restrict__ UE, const float* __restrict__ HGU,
                         const int* __restrict__ uui, const int* __restrict__ ucol,
                         float* __restrict__ fu) {
    int d = threadIdx.x;
    fu[d] = UE[(size_t)(*uui) * 128 + d] + HGU[(*ucol) * 128 + d];
}

// ---------------- out[i] = dot(FP[i,:], fu). grid P, block 128 ----------------
__global__ void k_outvec(const float* __restrict__ FP, const float* __restrict__ fu,
                         float* __restrict__ out) {
    __shared__ float red[128];
    size_t i = blockIdx.x;
    int d = threadIdx.x;
    red[d] = FP[i * 128 + d] * fu[d];
    __syncthreads();
    for (int s = 64; s > 0; s >>= 1) {
        if (d < s) red[d] += red[d + s];
        __syncthreads();
    }
    if (d == 0) out[i] = red[0];
}

// ---------------- pred_loss = LSE(out) - out[target], single block ----------------
__global__ void k_predloss(const float* __restrict__ ov, const int* __restrict__ tgt,
                           float* __restrict__ loss) {
    __shared__ float red[256];
    int t = threadIdx.x;
    float m = -1e30f;
    for (int i = t; i < P; i += 256) m = fmaxf(m, ov[i]);
    red[t] = m;
    __syncthreads();
    for (int s = 128; s > 0; s >>= 1) {
        if (t < s) red[t] = fmaxf(red[t], red[t + s]);
        __syncthreads();
    }
    float mg = red[0];
    __syncthreads();
    float ssum = 0.f;
    for (int i = t; i < P; i += 256) ssum += __expf(ov[i] - mg);
    red[t] = ssum;
    __syncthreads();
    for (int s = 128; s > 0; s >>= 1) {
        if (t < s) red[t] += red[t + s];
        __syncthreads();
    }
    if (t == 0) {
        float lse = mg + logf(red[0]);
        atomAddF(loss, lse - ov[*tgt]);
    }
}

__global__ void k_writeloss(const float* __restrict__ sc, float* __restrict__ out) {
    out[0] = sc[0];
}

extern "C" void kernel_launch(void* const* d_in, const int* in_sizes, int n_in,
                              void* d_out, int out_size, void* d_ws, size_t ws_size,
                              hipStream_t stream) {
    const float* poi_w  = (const float*)d_in[0];
    const float* ui_w   = (const float*)d_in[1];
    const float* Wc     = (const float*)d_in[2];
    const float* bc     = (const float*)d_in[3];
    const float* WU     = (const float*)d_in[4];
    const float* bU     = (const float*)d_in[5];
    const float* cr     = (const float*)d_in[6];
    const float* ci     = (const float*)d_in[7];
    const float* HGpu   = (const float*)d_in[8];
    const float* HGup   = (const float*)d_in[9];
    const float* UI     = (const float*)d_in[10];
    const float* noise1 = (const float*)d_in[11];
    const float* noise2 = (const float*)d_in[12];
    const int* target   = (const int*)d_in[13];
    const int* ucol     = (const int*)d_in[14];
    const int* uui      = (const int*)d_in[15];
    float* out = (float*)d_out;

    float* ws = (float*)d_ws;
    size_t o = 0;
    auto alloc = [&](size_t n) { float* p = ws + o; o += n; return p; };
    float* H   = alloc((size_t)P * D);
    float* UE  = alloc((size_t)PU * D);
    float* B1  = alloc((size_t)PU * D);
    float* B2  = alloc((size_t)PU * D);
    float* B3  = alloc((size_t)PU * D);
    float* B4  = alloc((size_t)PU * D);
    float* G   = alloc((size_t)P * 512);
    float* PRE = alloc((size_t)P * D);
    float* TS  = alloc(NHE * D);
    float* HGU = alloc(NHE * D);
    float* CM  = alloc(D * D);
    float* SM  = alloc(D * D);
    float* WR  = alloc(512 * D);
    float* WI  = alloc(512 * D);
    float* IN1 = alloc(PU);
    float* IN2 = alloc(PU);
    float* RS  = alloc(PU);
    float* CS  = alloc(PU);
    float* SC  = alloc(16);
    float* FU  = alloc(D);
    if (o * sizeof(float) > ws_size) return;  // workspace too small: bail safely

    auto Z = [&](float* p, size_t n) { hipMemsetAsync(p, 0, n * sizeof(float), stream); };
    auto GEMM = [&](const float* A, int lda, const float* B, float* C, int M, int K,
                    int ysplit, float alpha) {
        int klen = (K + ysplit - 1) / ysplit;
        dim3 g((M + 63) / 64, ysplit);
        k_gemm<<<g, 256, 0, stream>>>(A, lda, B, C, M, K, alpha, klen);
    };
    const int EW_P  = (P * D + 255) / 256;
    const int EW_PU = (PU * D + 255) / 256;

    Z(SC, 16);
    k_tables<<<(D * D + 255) / 256, 256, 0, stream>>>(CM, SM);
    k_reshape<<<(512 * D + 255) / 256, 256, 0, stream>>>(cr, ci, WR, WI);

    // ---- gates ----
    Z(B2, (size_t)PU * D);
    GEMM(poi_w, D, Wc, B2, P, D, 2, 1.f);
    k_gate_ep<<<EW_P, 256, 0, stream>>>(poi_w, B2, bc, B1, P * D);   // col_gate -> B1
    Z(B2, (size_t)PU * D);
    GEMM(ui_w, D, WU, B2, PU, D, 2, 1.f);
    k_gate_ep<<<EW_PU, 256, 0, stream>>>(ui_w, B2, bU, B3, PU * D);  // U_gate -> B3

    // ---- hconv -> H ----
    Z(TS, NHE * D);
    k_small_pu<<<dim3(NHE, 16), 256, 0, stream>>>(HGpu, B1, TS, P);
    Z(B2, (size_t)P * D);
    GEMM(HGup, NHE, TS, B2, P, NHE, 1, 1.f);                         // e1 -> B2
    Z(TS, NHE * D);
    k_small_pu<<<dim3(NHE, 16), 256, 0, stream>>>(HGpu, B2, TS, P);
    Z(B4, (size_t)P * D);
    GEMM(HGup, NHE, TS, B4, P, NHE, 1, 1.f);                         // e2 -> B4
    k_acc3norm<<<P, 128, 0, stream>>>(B1, B2, B4, H);

    // ---- hg_users ----
    Z(HGU, NHE * D);
    k_small_pu<<<dim3(NHE, 16), 256, 0, stream>>>(HGpu, H, HGU, P);

    // ---- level_loss = info_nce(H, H + noise1) ----
    k_add<<<EW_P, 256, 0, stream>>>(H, noise1, B2, P * D);
    k_invnorm<<<P, 128, 0, stream>>>(H, IN1);
    k_invnorm<<<P, 128, 0, stream>>>(B2, IN2);
    Z(RS, PU); Z(CS, PU);
    k_rowcol<<<dim3(64, 64), 256, 0, stream>>>(H, IN1, P, B2, IN2, P, RS, CS, SC + 1);
    k_nce_reduce<<<32, 256, 0, stream>>>(RS, CS, SC + 1, P, SC);

    // ---- gconv -> UE ----
    Z(B2, (size_t)PU * D);
    GEMM(UI, PU, B3, B2, PU, PU, 8, 1.f);                            // e1 -> B2
    Z(B4, (size_t)PU * D);
    GEMM(UI, PU, B2, B4, PU, PU, 8, 1.f);                            // e2 -> B4
    k_acc3norm<<<PU, 128, 0, stream>>>(B3, B2, B4, UE);

    // ---- level_loss1 = info_nce(UE, UE + noise2) ----
    k_add<<<EW_PU, 256, 0, stream>>>(UE, noise2, B2, PU * D);
    k_invnorm<<<PU, 128, 0, stream>>>(UE, IN1);
    k_invnorm<<<PU, 128, 0, stream>>>(B2, IN2);
    Z(RS, PU); Z(CS, PU);
    k_rowcol<<<dim3(65, 65), 256, 0, stream>>>(UE, IN1, PU, B2, IN2, PU, RS, CS, SC + 2);
    k_nce_reduce<<<32, 256, 0, stream>>>(RS, CS, SC + 2, PU, SC);

    // ---- ssl_p = info_nce(H, poi_e) ----
    const float* poi_e = UE + (size_t)NUC * D;
    k_invnorm<<<P, 128, 0, stream>>>(H, IN1);
    k_invnorm<<<P, 128, 0, stream>>>(poi_e, IN2);
    Z(RS, PU); Z(CS, PU);
    k_rowcol<<<dim3(64, 64), 256, 0, stream>>>(H, IN1, P, poi_e, IN2, P, RS, CS, SC + 3);
    k_nce_reduce<<<32, 256, 0, stream>>>(RS, CS, SC + 3, P, SC);

    // ---- ssl (tiny) ----
    k_ssl<<<1, 256, 0, stream>>>(UE, HGU, SC);

    // ---- gated_kan ----
    Z(B1, (size_t)P * D); GEMM(H, D, CM, B1, P, D, 2, 1.f);          // X1R
    Z(B2, (size_t)P * D); GEMM(H, D, SM, B2, P, D, 2, 1.f);          // X1I
    Z(B3, (size_t)P * D); GEMM(poi_e, D, CM, B3, P, D, 2, 1.f);      // X2R
    Z(B4, (size_t)P * D); GEMM(poi_e, D, SM, B4, P, D, 2, 1.f);      // X2I
    k_features<<<EW_P, 256, 0, stream>>>(B1, B3, G, P * D);
    Z(PRE, (size_t)P * D);
    GEMM(G, 512, WR, PRE, P, 512, 4, 1.f);
    k_mix<<<EW_P, 256, 0, stream>>>(PRE, B1, B3, P * D);             // fr -> B1
    k_features<<<EW_P, 256, 0, stream>>>(B2, B4, G, P * D);
    Z(PRE, (size_t)P * D);
    GEMM(G, 512, WI, PRE, P, 512, 4, 1.f);
    k_mix<<<EW_P, 256, 0, stream>>>(PRE, B2, B4, P * D);             // fi -> B2
    Z(B3, (size_t)P * D);
    GEMM(B1, D, CM, B3, P, D, 2, 1.f / 128.f);                       // final_p  = fr@C/128
    GEMM(B2, D, SM, B3, P, D, 2, 1.f / 128.f);                       //         += fi@(-S)/128

    // ---- final output + pred_loss ----
    k_finalu<<<1, 128, 0, stream>>>(UE, HGU, uui, ucol, FU);
    k_outvec<<<P, 128, 0, stream>>>(B3, FU, out + 1);
    k_predloss<<<1, 256, 0, stream>>>(out + 1, target, SC);
    k_writeloss<<<1, 1, 0, stream>>>(SC, out);
}

// Round 2
// 1518.724 us; speedup vs baseline: 2.8120x; 2.8120x over previous
//
#include <hip/hip_runtime.h>
#include <math.h>

#define D 128
#define P 8192
#define PU 8234
#define NHE 51
#define NUC 42
#define KP 8256  // PU rounded up to multiple of 32 (zero-padded K for bf16 B^T)

typedef __attribute__((ext_vector_type(8))) short short8v;
typedef __attribute__((ext_vector_type(8))) unsigned short ushort8v;
typedef __attribute__((ext_vector_type(4))) float f32x4;

__device__ inline void atomAddF(float* p, float v) {
#if defined(__HIP_PLATFORM_AMD__)
    unsafeAtomicAdd(p, v);
#else
    atomicAdd(p, v);
#endif
}

// f32 -> bf16 round-to-nearest-even
__device__ inline unsigned short bfr(float f) {
    unsigned int u = __float_as_uint(f);
    u += 0x7fffu + ((u >> 16) & 1u);
    return (unsigned short)(u >> 16);
}

// ---------------- tables: Cm[k*128+t]=cos(2*pi*k*t/128), Sm = -sin ----------------
__global__ void k_tables(float* Cm, float* Sm) {
    int idx = blockIdx.x * 256 + threadIdx.x;
    if (idx >= D * D) return;
    int k = idx >> 7, t = idx & 127;
    int m = (k * t) & 127;
    float ang = (float)m * 0.049087385212340517f; // 2*pi/128
    Cm[idx] = cosf(ang);
    Sm[idx] = -sinf(ang);
}

// ---------------- reshape cheby coeffs (i,o,k) -> W[(i*4+k)*128+o] ----------------
__global__ void k_reshape(const float* __restrict__ cr, const float* __restrict__ ci,
                          float* __restrict__ Wr, float* __restrict__ Wi) {
    int idx = blockIdx.x * 256 + threadIdx.x;
    if (idx >= 512 * D) return;
    int o = idx & 127;
    int ik = idx >> 7;
    int i = ik >> 2, kk = ik & 3;
    Wr[idx] = cr[(i * 128 + o) * 4 + kk];
    Wi[idx] = ci[(i * 128 + o) * 4 + kk];
}

// ---------------- generic fp32 GEMM: C[M x 128] += alpha * A[M x K] @ B[K x 128] ----------------
#define GEMM_BODY(K_)                                                     \
    {                                                                     \
        float a[4], b[8];                                                 \
        _Pragma("unroll") for (int r = 0; r < 4; r++) a[r] = As[ty + 16 * r][K_]; \
        _Pragma("unroll") for (int c = 0; c < 8; c++) b[c] = Bs[K_][tx + 16 * c]; \
        _Pragma("unroll") for (int r = 0; r < 4; r++)                     \
            _Pragma("unroll") for (int c = 0; c < 8; c++)                 \
                acc[r][c] += a[r] * b[c];                                 \
    }

__global__ __launch_bounds__(256) void k_gemm(const float* __restrict__ A, int lda,
                                              const float* __restrict__ B,
                                              float* __restrict__ C,
                                              int M, int K, float alpha, int klen) {
    __shared__ float As[64][33];
    __shared__ float Bs[32][128];
    const int t = threadIdx.x;
    const int tx = t & 15, ty = t >> 4;
    const int i0 = blockIdx.x * 64;
    const int kbeg = blockIdx.y * klen;
    const int kend = min(K, kbeg + klen);
    float acc[4][8];
#pragma unroll
    for (int r = 0; r < 4; r++)
#pragma unroll
        for (int c = 0; c < 8; c++) acc[r][c] = 0.f;

    for (int k0 = kbeg; k0 < kend; k0 += 32) {
#pragma unroll
        for (int q = 0; q < 2; q++) {
            int idx = t + q * 256;
            int row = idx >> 3;
            int col = (idx & 7) * 4;
            int gi = i0 + row;
#pragma unroll
            for (int u = 0; u < 4; u++) {
                int gk = k0 + col + u;
                As[row][col + u] = (gi < M && gk < kend) ? A[(size_t)gi * lda + gk] : 0.f;
            }
        }
#pragma unroll
        for (int q = 0; q < 4; q++) {
            int idx = t + q * 256;
            int row = idx >> 5;
            int col4 = (idx & 31) * 4;
            int gk = k0 + row;
            float4 v = make_float4(0.f, 0.f, 0.f, 0.f);
            if (gk < kend) v = *reinterpret_cast<const float4*>(B + (size_t)gk * 128 + col4);
            *reinterpret_cast<float4*>(&Bs[row][col4]) = v;
        }
        __syncthreads();
        int klim = min(32, kend - k0);
        if (klim == 32) {
#pragma unroll
            for (int k = 0; k < 32; k++) GEMM_BODY(k)
        } else {
            for (int k = 0; k < klim; k++) GEMM_BODY(k)
        }
        __syncthreads();
    }
#pragma unroll
    for (int r = 0; r < 4; r++) {
        int gi = i0 + ty + 16 * r;
        if (gi < M) {
#pragma unroll
            for (int c = 0; c < 8; c++)
                atomAddF(&C[(size_t)gi * 128 + tx + 16 * c], alpha * acc[r][c]);
        }
    }
}

// ---------------- T[i,:] += HG_pu[i,:] @ X  (i < NHE). grid (NHE, chunks) ----------------
__global__ void k_small_pu(const float* __restrict__ PUm, const float* __restrict__ X,
                           float* __restrict__ T, int Kn) {
    int i = blockIdx.x;
    int klen = (Kn + gridDim.y - 1) / gridDim.y;
    int kbeg = blockIdx.y * klen;
    int kend = min(Kn, kbeg + klen);
    int t = threadIdx.x;
    int d = t & 127, half = t >> 7;
    float acc = 0.f;
    for (int k = kbeg + half; k < kend; k += 2)
        acc += PUm[(size_t)i * Kn + k] * X[(size_t)k * 128 + d];
    atomAddF(&T[i * 128 + d], acc);
}

// ---------------- gate epilogue: out = X * sigmoid(pre + bias) ----------------
__global__ void k_gate_ep(const float* __restrict__ X, const float* __restrict__ pre,
                          const float* __restrict__ bias, float* __restrict__ out, int n) {
    int idx = blockIdx.x * 256 + threadIdx.x;
    if (idx < n) {
        float s = pre[idx] + bias[idx & 127];
        s = 1.f / (1.f + expf(-s));
        out[idx] = X[idx] * s;
    }
}

// ---------------- out = l2norm((a+b+c)/3) per row. grid nrows, block 128 ----------------
__global__ void k_acc3norm(const float* __restrict__ a, const float* __restrict__ b,
                           const float* __restrict__ c, float* __restrict__ out) {
    __shared__ float red[128];
    size_t i = blockIdx.x;
    int d = threadIdx.x;
    float v = (a[i * 128 + d] + b[i * 128 + d] + c[i * 128 + d]) * (1.f / 3.f);
    red[d] = v * v;
    __syncthreads();
    for (int s = 64; s > 0; s >>= 1) {
        if (d < s) red[d] += red[d + s];
        __syncthreads();
    }
    float inv = 1.f / fmaxf(sqrtf(red[0]), 1e-12f);
    out[i * 128 + d] = v * inv;
}

// ---------------- prep for NCE: Zb = bf16( scale * l2norm(X (+Yadd)) ) ----------------
__global__ void k_prep(const float* __restrict__ X, const float* __restrict__ Yadd,
                       float scale, unsigned short* __restrict__ Zb) {
    __shared__ float red[128];
    size_t i = blockIdx.x;
    int d = threadIdx.x;
    float v = X[i * 128 + d];
    if (Yadd) v += Yadd[i * 128 + d];
    red[d] = v * v;
    __syncthreads();
    for (int s = 64; s > 0; s >>= 1) {
        if (d < s) red[d] += red[d + s];
        __syncthreads();
    }
    float inv = scale / fmaxf(sqrtf(red[0]), 1e-12f);
    Zb[i * 128 + d] = bfr(v * inv);
}

// ---------------- fused InfoNCE tile pass (bf16 MFMA) ----------------
// Za rows already scaled by 5/||.||, Zb rows by 1/||.||. Accumulates exp row/col
// sums and diag sum. grid (ceil(n1/128), ceil(n2/128)), block 256 (4 waves, 2x2).
__global__ __launch_bounds__(256) void k_rowcol_mfma(
    const unsigned short* __restrict__ Za, int n1,
    const unsigned short* __restrict__ Zb, int n2,
    float* __restrict__ rowsum, float* __restrict__ colsum, float* __restrict__ diagsum) {
    // 128x128 bf16 tiles, stored as 16B chunks with XOR swizzle (chunk c of row r
    // lives at c ^ (r&15)) so the 16 lanes of a fragment read hit 16 distinct banks.
    __shared__ ushort8v As[2048];
    __shared__ ushort8v Bs[2048];
    const int t = threadIdx.x;
    const int i0 = blockIdx.x * 128, j0 = blockIdx.y * 128;
#pragma unroll
    for (int u = 0; u < 8; ++u) {
        int g = t + u * 256;
        int row = g >> 4, c = g & 15;
        int sw = (row << 4) | (c ^ (row & 15));
        ushort8v va = (ushort8v){0, 0, 0, 0, 0, 0, 0, 0};
        ushort8v vb = va;
        if (i0 + row < n1) va = *(const ushort8v*)(Za + ((size_t)(i0 + row) << 7) + c * 8);
        if (j0 + row < n2) vb = *(const ushort8v*)(Zb + ((size_t)(j0 + row) << 7) + c * 8);
        As[sw] = va;
        Bs[sw] = vb;
    }
    __syncthreads();
    const int l = t & 63, w = t >> 6;
    const int wy = w >> 1, wx = w & 1;
    const int lr = l & 15, lg = l >> 4;
    f32x4 acc[4][4];
#pragma unroll
    for (int mi = 0; mi < 4; ++mi)
#pragma unroll
        for (int ni = 0; ni < 4; ++ni) acc[mi][ni] = (f32x4){0.f, 0.f, 0.f, 0.f};

#pragma unroll
    for (int ks = 0; ks < 4; ++ks) {
        short8v a[4], b[4];
        int c = ks * 4 + lg;
#pragma unroll
        for (int mi = 0; mi < 4; ++mi) {
            int r = wy * 64 + mi * 16 + lr;
            a[mi] = __builtin_bit_cast(short8v, As[(r << 4) | (c ^ (r & 15))]);
            int r2 = wx * 64 + mi * 16 + lr;
            b[mi] = __builtin_bit_cast(short8v, Bs[(r2 << 4) | (c ^ (r2 & 15))]);
        }
#pragma unroll
        for (int mi = 0; mi < 4; ++mi)
#pragma unroll
            for (int ni = 0; ni < 4; ++ni)
                acc[mi][ni] = __builtin_amdgcn_mfma_f32_16x16x32_bf16(a[mi], b[ni], acc[mi][ni], 0, 0, 0);
    }
    // epilogue: exp + masked row/col/diag partials, shuffle-reduced.
    // C/D layout: col = lane&15, row = (lane>>4)*4 + reg  [m89 verified]
    float colp[4] = {0.f, 0.f, 0.f, 0.f};
    float dsum = 0.f;
#pragma unroll
    for (int mi = 0; mi < 4; ++mi) {
#pragma unroll
        for (int rg = 0; rg < 4; ++rg) {
            int grow = i0 + wy * 64 + mi * 16 + lg * 4 + rg;
            float rowp = 0.f;
#pragma unroll
            for (int ni = 0; ni < 4; ++ni) {
                int gcol = j0 + wx * 64 + ni * 16 + lr;
                float v = acc[mi][ni][rg];
                bool ok = (grow < n1) && (gcol < n2);
                float e = ok ? __expf(v) : 0.f;
                rowp += e;
                colp[ni] += e;
                if (ok && grow == gcol) dsum += v;
            }
            rowp += __shfl_xor(rowp, 1);
            rowp += __shfl_xor(rowp, 2);
            rowp += __shfl_xor(rowp, 4);
            rowp += __shfl_xor(rowp, 8);
            if (lr == 0 && grow < n1) atomAddF(&rowsum[grow], rowp);
        }
    }
#pragma unroll
    for (int ni = 0; ni < 4; ++ni) {
        float cp = colp[ni];
        cp += __shfl_xor(cp, 16);
        cp += __shfl_xor(cp, 32);
        int gcol = j0 + wx * 64 + ni * 16 + lr;
        if (lg == 0 && gcol < n2) atomAddF(&colsum[gcol], cp);
    }
    if (blockIdx.x == blockIdx.y) {
        dsum += __shfl_xor(dsum, 1);
        dsum += __shfl_xor(dsum, 2);
        dsum += __shfl_xor(dsum, 4);
        dsum += __shfl_xor(dsum, 8);
        dsum += __shfl_xor(dsum, 16);
        dsum += __shfl_xor(dsum, 32);
        if (l == 0) atomAddF(diagsum, dsum);
    }
}

// ---------------- transpose+convert: Bt[c][kp] = bf16(B[kp][c]), zero-padded to KP ----------------
__global__ __launch_bounds__(256) void k_tconv(const float* __restrict__ B,
                                               unsigned short* __restrict__ Bt, int K) {
    __shared__ float tile[32][33];
    int tx = threadIdx.x & 31, ty = threadIdx.x >> 5;  // ty 0..7
    int k0 = blockIdx.x * 32, c0 = blockIdx.y * 32;
#pragma unroll
    for (int q = 0; q < 4; ++q) {
        int k = k0 + ty + q * 8;
        tile[ty + q * 8][tx] = (k < K) ? B[(size_t)k * 128 + c0 + tx] : 0.f;
    }
    __syncthreads();
#pragma unroll
    for (int q = 0; q < 4; ++q) {
        int c = c0 + ty + q * 8;
        Bt[(size_t)c * KP + k0 + tx] = bfr(tile[tx][ty + q * 8]);
    }
}

// ---------------- gconv MFMA: C[M x 128] += A[M x K fp32] @ Bt[128 x KP bf16]^T ----------------
// A converted to bf16 in-flight (saves a 400MB conversion pass; A read exactly once).
// grid (ceil(M/128), ksplit), block 256 (4 waves, each 32 rows x 128 cols).
__global__ __launch_bounds__(256) void k_gconv(const float* __restrict__ A,
                                               const unsigned short* __restrict__ Bt,
                                               float* __restrict__ C,
                                               int M, int K, int klen) {
    const int t = threadIdx.x;
    const int l = t & 63, w = t >> 6;
    const int lr = l & 15, lg = l >> 4;
    const int r0 = blockIdx.x * 128 + w * 32;
    const int kbeg = blockIdx.y * klen;
    const int kend = min(K, kbeg + klen);
    f32x4 acc[2][8];
#pragma unroll
    for (int mi = 0; mi < 2; ++mi)
#pragma unroll
        for (int ni = 0; ni < 8; ++ni) acc[mi][ni] = (f32x4){0.f, 0.f, 0.f, 0.f};
    size_t rA[2];
    rA[0] = (size_t)min(r0 + lr, M - 1) * (size_t)K;       // clamp: OOB rows discarded at store
    rA[1] = (size_t)min(r0 + 16 + lr, M - 1) * (size_t)K;

    for (int k0 = kbeg; k0 < kend; k0 += 32) {
        int kf = k0 + lg * 8;
        short8v a[2];
        if (kf + 8 <= K) {
#pragma unroll
            for (int mi = 0; mi < 2; ++mi) {
                const float* p = A + rA[mi] + kf;  // 8B-aligned (kf mult of 8); lda odd -> float2
                float2 f0 = *(const float2*)(p);
                float2 f1 = *(const float2*)(p + 2);
                float2 f2 = *(const float2*)(p + 4);
                float2 f3 = *(const float2*)(p + 6);
                short8v v;
                v[0] = (short)bfr(f0.x); v[1] = (short)bfr(f0.y);
                v[2] = (short)bfr(f1.x); v[3] = (short)bfr(f1.y);
                v[4] = (short)bfr(f2.x); v[5] = (short)bfr(f2.y);
                v[6] = (short)bfr(f3.x); v[7] = (short)bfr(f3.y);
                a[mi] = v;
            }
        } else {  // K tail: per-element guard; Bt is zero-padded there anyway
#pragma unroll
            for (int mi = 0; mi < 2; ++mi) {
                short8v v;
#pragma unroll
                for (int j = 0; j < 8; ++j) {
                    int kk = kf + j;
                    v[j] = (kk < K) ? (short)bfr(A[rA[mi] + kk]) : (short)0;
                }
                a[mi] = v;
            }
        }
        short8v b[8];
#pragma unroll
        for (int ni = 0; ni < 8; ++ni)
            b[ni] = *(const short8v*)(Bt + (size_t)(ni * 16 + lr) * KP + kf);
#pragma unroll
        for (int mi = 0; mi < 2; ++mi)
#pragma unroll
            for (int ni = 0; ni < 8; ++ni)
                acc[mi][ni] = __builtin_amdgcn_mfma_f32_16x16x32_bf16(a[mi], b[ni], acc[mi][ni], 0, 0, 0);
    }
#pragma unroll
    for (int mi = 0; mi < 2; ++mi) {
#pragma unroll
        for (int rg = 0; rg < 4; ++rg) {
            int gr = r0 + mi * 16 + lg * 4 + rg;
            if (gr < M) {
#pragma unroll
                for (int ni = 0; ni < 8; ++ni)
                    atomAddF(&C[(size_t)gr * 128 + ni * 16 + lr], acc[mi][ni][rg]);
            }
        }
    }
}

// ---------------- reduce InfoNCE: loss += 0.5*mean(log rs + log cs) - diag/n ----------------
__global__ void k_nce_reduce(const float* __restrict__ rs, const float* __restrict__ cs,
                             const float* __restrict__ diag, int n, float* __restrict__ loss) {
    __shared__ float red[256];
    int t = threadIdx.x;
    float s = 0.f;
    for (int i = blockIdx.x * 256 + t; i < n; i += gridDim.x * 256)
        s += logf(rs[i]) + logf(cs[i]);
    red[t] = s;
    __syncthreads();
    for (int st = 128; st > 0; st >>= 1) {
        if (t < st) red[t] += red[t + st];
        __syncthreads();
    }
    if (t == 0) {
        float v = 0.5f * red[0] / (float)n;
        if (blockIdx.x == 0) v -= diag[0] / (float)n;
        atomAddF(loss, v);
    }
}

// ---------------- small InfoNCE (42x42), single block ----------------
__global__ void k_ssl(const float* __restrict__ UE, const float* __restrict__ HGU,
                      float* __restrict__ loss) {
    __shared__ float A[NUC][128], B[NUC][128];
    __shared__ float sim[NUC][NUC];
    __shared__ float invA[NUC], invB[NUC];
    __shared__ float pr[64];
    int t = threadIdx.x;
    for (int idx = t; idx < NUC * 128; idx += 256) {
        A[idx >> 7][idx & 127] = UE[idx];
        B[idx >> 7][idx & 127] = HGU[9 * 128 + idx];
    }
    __syncthreads();
    if (t < 2 * NUC) {
        int i = (t < NUC) ? t : t - NUC;
        float s = 0.f;
        if (t < NUC) {
            for (int d = 0; d < 128; d++) { float v = A[i][d]; s += v * v; }
            invA[i] = 1.f / fmaxf(sqrtf(s), 1e-12f);
        } else {
            for (int d = 0; d < 128; d++) { float v = B[i][d]; s += v * v; }
            invB[i] = 1.f / fmaxf(sqrtf(s), 1e-12f);
        }
    }
    __syncthreads();
    for (int idx = t; idx < NUC * NUC; idx += 256) {
        int i = idx / NUC, j = idx % NUC;
        float s = 0.f;
        for (int d = 0; d < 128; d++) s += A[i][d] * B[j][d];
        sim[i][j] = s * invA[i] * invB[j] * 5.0f;
    }
    __syncthreads();
    float part = 0.f;
    if (t < NUC) {
        float rsu = 0.f, csu = 0.f;
        for (int j = 0; j < NUC; j++) {
            rsu += __expf(sim[t][j]);
            csu += __expf(sim[j][t]);
        }
        part = 0.5f * (logf(rsu) + logf(csu)) - sim[t][t];
    }
    if (t < 64) pr[t] = (t < NUC) ? part : 0.f;
    __syncthreads();
    if (t == 0) {
        float s = 0.f;
        for (int i = 0; i < NUC; i++) s += pr[i];
        atomAddF(loss, s / (float)NUC);
    }
}

// ---------------- cheby features ----------------
__global__ void k_features(const float* __restrict__ Xa, const float* __restrict__ Xb,
                           float* __restrict__ G, int n) {
    int idx = blockIdx.x * 256 + threadIdx.x;
    if (idx < n) {
        float x1 = tanhf(Xa[idx]), x2 = tanhf(Xb[idx]);
        float4 w;
        w.x = 2.0f;
        w.y = x1 + x2;
        w.z = (2.f * x1 * x1 - 1.f) + (2.f * x2 * x2 - 1.f);
        w.w = x1 * (4.f * x1 * x1 - 3.f) + x2 * (4.f * x2 * x2 - 3.f);
        *reinterpret_cast<float4*>(G + (size_t)idx * 4) = w;
    }
}

// ---------------- mix: a = sig(pre)*a + (1-sig)*b ----------------
__global__ void k_mix(const float* __restrict__ pre, float* __restrict__ a,
                      const float* __restrict__ b, int n) {
    int idx = blockIdx.x * 256 + threadIdx.x;
    if (idx < n) {
        float g = 1.f / (1.f + expf(-pre[idx]));
        a[idx] = g * a[idx] + (1.f - g) * b[idx];
    }
}

__global__ void k_finalu(const float* __restrict__ UE, const float* __restrict__ HGU,
                         const int* __restrict__ uui, const int* __restrict__ ucol,
                         float* __restrict__ fu) {
    int d = threadIdx.x;
    fu[d] = UE[(size_t)(*uui) * 128 + d] + HGU[(*ucol) * 128 + d];
}

__global__ void k_outvec(const float* __restrict__ FP, const float* __restrict__ fu,
                         float* __restrict__ out) {
    __shared__ float red[128];
    size_t i = blockIdx.x;
    int d = threadIdx.x;
    red[d] = FP[i * 128 + d] * fu[d];
    __syncthreads();
    for (int s = 64; s > 0; s >>= 1) {
        if (d < s) red[d] += red[d + s];
        __syncthreads();
    }
    if (d == 0) out[i] = red[0];
}

__global__ void k_predloss(const float* __restrict__ ov, const int* __restrict__ tgt,
                           float* __restrict__ loss) {
    __shared__ float red[256];
    int t = threadIdx.x;
    float m = -1e30f;
    for (int i = t; i < P; i += 256) m = fmaxf(m, ov[i]);
    red[t] = m;
    __syncthreads();
    for (int s = 128; s > 0; s >>= 1) {
        if (t < s) red[t] = fmaxf(red[t], red[t + s]);
        __syncthreads();
    }
    float mg = red[0];
    __syncthreads();
    float ssum = 0.f;
    for (int i = t; i < P; i += 256) ssum += __expf(ov[i] - mg);
    red[t] = ssum;
    __syncthreads();
    for (int s = 128; s > 0; s >>= 1) {
        if (t < s) red[t] += red[t + s];
        __syncthreads();
    }
    if (t == 0) {
        float lse = mg + logf(red[0]);
        atomAddF(loss, lse - ov[*tgt]);
    }
}

__global__ void k_writeloss(const float* __restrict__ sc, float* __restrict__ out) {
    out[0] = sc[0];
}

extern "C" void kernel_launch(void* const* d_in, const int* in_sizes, int n_in,
                              void* d_out, int out_size, void* d_ws, size_t ws_size,
                              hipStream_t stream) {
    const float* poi_w  = (const float*)d_in[0];
    const float* ui_w   = (const float*)d_in[1];
    const float* Wc     = (const float*)d_in[2];
    const float* bc     = (const float*)d_in[3];
    const float* WU     = (const float*)d_in[4];
    const float* bU     = (const float*)d_in[5];
    const float* cr     = (const float*)d_in[6];
    const float* ci     = (const float*)d_in[7];
    const float* HGpu   = (const float*)d_in[8];
    const float* HGup   = (const float*)d_in[9];
    const float* UI     = (const float*)d_in[10];
    const float* noise1 = (const float*)d_in[11];
    const float* noise2 = (const float*)d_in[12];
    const int* target   = (const int*)d_in[13];
    const int* ucol     = (const int*)d_in[14];
    const int* uui      = (const int*)d_in[15];
    float* out = (float*)d_out;

    float* ws = (float*)d_ws;
    size_t o = 0;
    auto alloc = [&](size_t n) { float* p = ws + o; o += n; return p; };
    float* H   = alloc((size_t)P * D);
    float* UE  = alloc((size_t)PU * D);
    float* B1  = alloc((size_t)PU * D);
    float* B2  = alloc((size_t)PU * D);
    float* B3  = alloc((size_t)PU * D);
    float* B4  = alloc((size_t)PU * D);
    float* G   = alloc((size_t)P * 512);
    float* PRE = alloc((size_t)P * D);
    float* TS  = alloc(NHE * D);
    float* HGU = alloc(NHE * D);
    float* CM  = alloc(D * D);
    float* SM  = alloc(D * D);
    float* WR  = alloc(512 * D);
    float* WI  = alloc(512 * D);
    float* RS  = alloc(8240);
    float* CS  = alloc(8240);
    float* SC  = alloc(16);
    float* FU  = alloc(D);
    unsigned short* ZA = (unsigned short*)alloc((size_t)PU * D / 2);  // bf16 operand (x5 scaled)
    unsigned short* ZB = (unsigned short*)alloc((size_t)PU * D / 2);  // bf16 operand (x1)
    unsigned short* ZC = (unsigned short*)alloc((size_t)PU * D / 2);  // bf16 operand (x5, UE)
    unsigned short* BT = (unsigned short*)alloc((size_t)D * KP / 2);  // bf16 B^T, zero-padded K
    if (o * sizeof(float) > ws_size) return;  // workspace too small: bail safely

    auto Z = [&](float* p, size_t n) { hipMemsetAsync(p, 0, n * sizeof(float), stream); };
    auto GEMM = [&](const float* A, int lda, const float* B, float* C, int M, int K,
                    int ysplit, float alpha) {
        int klen = (K + ysplit - 1) / ysplit;
        dim3 g((M + 63) / 64, ysplit);
        k_gemm<<<g, 256, 0, stream>>>(A, lda, B, C, M, K, alpha, klen);
    };
    auto GCONV = [&](const float* Xin, float* Cout) {
        // Cout (zeroed) += UI @ Xin via bf16 MFMA
        k_tconv<<<dim3(KP / 32, 4), 256, 0, stream>>>(Xin, BT, PU);
        int ksplit = 8;
        int klen = ((PU + ksplit - 1) / ksplit + 31) & ~31;  // 1056
        k_gconv<<<dim3((PU + 127) / 128, ksplit), 256, 0, stream>>>(UI, BT, Cout, PU, PU, klen);
    };
    auto NCE = [&](const unsigned short* z1, int n1, const unsigned short* z2, int n2,
                   float* dslot) {
        Z(RS, n1); Z(CS, n2);
        dim3 g((n1 + 127) / 128, (n2 + 127) / 128);
        k_rowcol_mfma<<<g, 256, 0, stream>>>(z1, n1, z2, n2, RS, CS, dslot);
        k_nce_reduce<<<32, 256, 0, stream>>>(RS, CS, dslot, n1, SC);
    };
    const int EW_P  = (P * D + 255) / 256;
    const int EW_PU = (PU * D + 255) / 256;

    Z(SC, 16);
    k_tables<<<(D * D + 255) / 256, 256, 0, stream>>>(CM, SM);
    k_reshape<<<(512 * D + 255) / 256, 256, 0, stream>>>(cr, ci, WR, WI);

    // ---- gates ----
    Z(B2, (size_t)PU * D);
    GEMM(poi_w, D, Wc, B2, P, D, 2, 1.f);
    k_gate_ep<<<EW_P, 256, 0, stream>>>(poi_w, B2, bc, B1, P * D);   // col_gate -> B1
    Z(B2, (size_t)PU * D);
    GEMM(ui_w, D, WU, B2, PU, D, 2, 1.f);
    k_gate_ep<<<EW_PU, 256, 0, stream>>>(ui_w, B2, bU, B3, PU * D);  // U_gate -> B3

    // ---- hconv -> H ----
    Z(TS, NHE * D);
    k_small_pu<<<dim3(NHE, 16), 256, 0, stream>>>(HGpu, B1, TS, P);
    Z(B2, (size_t)P * D);
    GEMM(HGup, NHE, TS, B2, P, NHE, 1, 1.f);                         // e1 -> B2
    Z(TS, NHE * D);
    k_small_pu<<<dim3(NHE, 16), 256, 0, stream>>>(HGpu, B2, TS, P);
    Z(B4, (size_t)P * D);
    GEMM(HGup, NHE, TS, B4, P, NHE, 1, 1.f);                         // e2 -> B4
    k_acc3norm<<<P, 128, 0, stream>>>(B1, B2, B4, H);

    // ---- hg_users ----
    Z(HGU, NHE * D);
    k_small_pu<<<dim3(NHE, 16), 256, 0, stream>>>(HGpu, H, HGU, P);

    // ---- level_loss = info_nce(H, H + noise1) ----
    k_prep<<<P, 128, 0, stream>>>(H, nullptr, 5.f, ZA);   // ZA = 5*norm(H), reused in ssl_p
    k_prep<<<P, 128, 0, stream>>>(H, noise1, 1.f, ZB);
    NCE(ZA, P, ZB, P, SC + 1);

    // ---- gconv -> UE ----
    Z(B2, (size_t)PU * D);
    GCONV(B3, B2);                                                   // e1 -> B2
    Z(B4, (size_t)PU * D);
    GCONV(B2, B4);                                                   // e2 -> B4
    k_acc3norm<<<PU, 128, 0, stream>>>(B3, B2, B4, UE);

    // ---- level_loss1 = info_nce(UE, UE + noise2) ----
    k_prep<<<PU, 128, 0, stream>>>(UE, nullptr, 5.f, ZC);
    k_prep<<<PU, 128, 0, stream>>>(UE, noise2, 1.f, ZB);
    NCE(ZC, PU, ZB, PU, SC + 2);

    // ---- ssl_p = info_nce(H, poi_e) ----
    const float* poi_e = UE + (size_t)NUC * D;
    k_prep<<<P, 128, 0, stream>>>(poi_e, nullptr, 1.f, ZB);
    NCE(ZA, P, ZB, P, SC + 3);                                       // ZA still holds 5*norm(H)

    // ---- ssl (tiny) ----
    k_ssl<<<1, 256, 0, stream>>>(UE, HGU, SC);

    // ---- gated_kan ----
    Z(B1, (size_t)P * D); GEMM(H, D, CM, B1, P, D, 2, 1.f);          // X1R
    Z(B2, (size_t)P * D); GEMM(H, D, SM, B2, P, D, 2, 1.f);          // X1I
    Z(B3, (size_t)P * D); GEMM(poi_e, D, CM, B3, P, D, 2, 1.f);      // X2R
    Z(B4, (size_t)P * D); GEMM(poi_e, D, SM, B4, P, D, 2, 1.f);      // X2I
    k_features<<<EW_P, 256, 0, stream>>>(B1, B3, G, P * D);
    Z(PRE, (size_t)P * D);
    GEMM(G, 512, WR, PRE, P, 512, 4, 1.f);
    k_mix<<<EW_P, 256, 0, stream>>>(PRE, B1, B3, P * D);             // fr -> B1
    k_features<<<EW_P, 256, 0, stream>>>(B2, B4, G, P * D);
    Z(PRE, (size_t)P * D);
    GEMM(G, 512, WI, PRE, P, 512, 4, 1.f);
    k_mix<<<EW_P, 256, 0, stream>>>(PRE, B2, B4, P * D);             // fi -> B2
    Z(B3, (size_t)P * D);
    GEMM(B1, D, CM, B3, P, D, 2, 1.f / 128.f);                       // final_p  = fr@C/128
    GEMM(B2, D, SM, B3, P, D, 2, 1.f / 128.f);                       //         += fi@(-S)/128

    // ---- final output + pred_loss ----
    k_finalu<<<1, 128, 0, stream>>>(UE, HGU, uui, ucol, FU);
    k_outvec<<<P, 128, 0, stream>>>(B3, FU, out + 1);
    k_predloss<<<1, 256, 0, stream>>>(out + 1, target, SC);
    k_writeloss<<<1, 1, 0, stream>>>(SC, out);
}

// Round 3
// 1442.345 us; speedup vs baseline: 2.9609x; 1.0530x over previous
//
#include <hip/hip_runtime.h>
#include <math.h>

#define D 128
#define P 8192
#define PU 8234
#define NHE 51
#define NUC 42
#define KP 8256  // PU rounded up to multiple of 64 (zero-padded K for bf16 B^T)

typedef __attribute__((ext_vector_type(8))) short short8v;
typedef __attribute__((ext_vector_type(8))) unsigned short ushort8v;
typedef __attribute__((ext_vector_type(4))) unsigned short ushort4v;
typedef __attribute__((ext_vector_type(4))) float f32x4;

__device__ inline void atomAddF(float* p, float v) {
#if defined(__HIP_PLATFORM_AMD__)
    unsafeAtomicAdd(p, v);
#else
    atomicAdd(p, v);
#endif
}

// f32 -> bf16 round-to-nearest-even
__device__ inline unsigned short bfr(float f) {
    unsigned int u = __float_as_uint(f);
    u += 0x7fffu + ((u >> 16) & 1u);
    return (unsigned short)(u >> 16);
}
__device__ inline float b2f(unsigned short u) {
    return __uint_as_float(((unsigned int)u) << 16);
}
__device__ inline float sigf(float x) { return 1.f / (1.f + __expf(-x)); }

// =================== weight prep (bf16, transposed: Wt[n][k] = W[k][n]) ===================
__global__ void k_tables_bf(unsigned short* Ct, unsigned short* St) {
    int idx = blockIdx.x * 256 + threadIdx.x;
    if (idx >= D * D) return;
    int k = idx >> 7, t = idx & 127;
    int m = (k * t) & 127;
    float ang = (float)m * 0.049087385212340517f; // 2*pi/128; symmetric so Wt == W
    Ct[idx] = bfr(cosf(ang));
    St[idx] = bfr(-sinf(ang));
}

__global__ void k_reshape_bf(const float* __restrict__ cr, const float* __restrict__ ci,
                             unsigned short* __restrict__ WRt, unsigned short* __restrict__ WIt) {
    int idx = blockIdx.x * 256 + threadIdx.x;  // over [128 o][512 ik]
    if (idx >= 128 * 512) return;
    int o = idx >> 9, ik = idx & 511;
    int i = ik >> 2, kk = ik & 3;
    WRt[idx] = bfr(cr[(i * 128 + o) * 4 + kk]);
    WIt[idx] = bfr(ci[(i * 128 + o) * 4 + kk]);
}

__global__ void k_convW(const float* __restrict__ W, unsigned short* __restrict__ Wt) {
    int idx = blockIdx.x * 256 + threadIdx.x;
    if (idx >= D * D) return;
    int n = idx >> 7, k = idx & 127;
    Wt[idx] = bfr(W[k * 128 + n]);
}

// =================== shared MFMA-GEMM machinery (BM=64, BN=128, BK=64) ===================
// LDS tiles: rows x 64 bf16, 16B chunks XOR-swizzled: chunk c of row r at c^(r&7).
__device__ inline void mm_stage_B(const unsigned short* __restrict__ Bw, int ldb, int k0,
                                  unsigned short* Bls, int t) {
#pragma unroll
    for (int u = 0; u < 4; ++u) {
        int idx = u * 256 + t;
        int row = idx >> 3, c = idx & 7;
        ushort8v v = *(const ushort8v*)(Bw + (size_t)row * ldb + k0 + c * 8);
        *(ushort8v*)&Bls[row * 64 + ((c ^ (row & 7)) << 3)] = v;
    }
}

__device__ inline void mm_stage_A_f32(const float* __restrict__ A, int lda, int M, int r0,
                                      int k0, unsigned short* Als, int t) {
#pragma unroll
    for (int u = 0; u < 4; ++u) {
        int idx = u * 256 + t;
        int row = idx >> 4, c4 = idx & 15;
        int gr = r0 + row;
        float4 v = make_float4(0.f, 0.f, 0.f, 0.f);
        if (gr < M) v = *(const float4*)(A + (size_t)gr * lda + k0 + c4 * 4);
        ushort4v pv = {bfr(v.x), bfr(v.y), bfr(v.z), bfr(v.w)};
        *(ushort4v*)&Als[row * 64 + (((c4 >> 1) ^ (row & 7)) << 3) + ((c4 & 1) << 2)] = pv;
    }
}

__device__ inline void mm_stage_A_bf(const unsigned short* __restrict__ A, int lda, int M,
                                     int r0, int k0, unsigned short* Als, int t) {
#pragma unroll
    for (int u = 0; u < 2; ++u) {
        int idx = u * 256 + t;
        int row = idx >> 3, c = idx & 7;
        int gr = r0 + row;
        ushort8v v = (ushort8v){0, 0, 0, 0, 0, 0, 0, 0};
        if (gr < M) v = *(const ushort8v*)(A + (size_t)gr * lda + k0 + c * 8);
        *(ushort8v*)&Als[row * 64 + ((c ^ (row & 7)) << 3)] = v;
    }
}

__device__ inline void mm_tile_mfma(const unsigned short* Als, const unsigned short* Bls,
                                    int w, int lr, int lg, f32x4* acc) {
#pragma unroll
    for (int s = 0; s < 2; ++s) {
        int ch = s * 4 + lg;
        short8v a = *(const short8v*)&Als[(w * 16 + lr) * 64 + ((ch ^ (lr & 7)) << 3)];
#pragma unroll
        for (int ni = 0; ni < 8; ++ni) {
            short8v b = *(const short8v*)&Bls[(ni * 16 + lr) * 64 + ((ch ^ (lr & 7)) << 3)];
            acc[ni] = __builtin_amdgcn_mfma_f32_16x16x32_bf16(a, b, acc[ni], 0, 0, 0);
        }
    }
}

// ---------------- gate: out = A * sigmoid(A@Wt^T + bias). A fp32 [M][128] ----------------
__global__ __launch_bounds__(256) void k_mm_gate(const float* __restrict__ A,
                                                 const unsigned short* __restrict__ Wt,
                                                 const float* __restrict__ bias,
                                                 float* __restrict__ out, int M) {
    __shared__ ushort8v AV[512], BV[1024];
    unsigned short* Als = (unsigned short*)AV;
    unsigned short* Bls = (unsigned short*)BV;
    const int t = threadIdx.x, l = t & 63, w = t >> 6, lr = l & 15, lg = l >> 4;
    const int r0 = blockIdx.x * 64;
    f32x4 acc[8];
#pragma unroll
    for (int ni = 0; ni < 8; ++ni) acc[ni] = (f32x4){0.f, 0.f, 0.f, 0.f};
    for (int k0 = 0; k0 < 128; k0 += 64) {
        mm_stage_A_f32(A, 128, M, r0, k0, Als, t);
        mm_stage_B(Wt, 128, k0, Bls, t);
        __syncthreads();
        mm_tile_mfma(Als, Bls, w, lr, lg, acc);
        __syncthreads();
    }
#pragma unroll
    for (int ni = 0; ni < 8; ++ni) {
        int col = ni * 16 + lr;
        float bb = bias[col];
#pragma unroll
        for (int rg = 0; rg < 4; ++rg) {
            int grow = r0 + w * 16 + lg * 4 + rg;
            if (grow < M) {
                float x = A[(size_t)grow * 128 + col];
                out[(size_t)grow * 128 + col] = x * sigf(acc[ni][rg] + bb);
            }
        }
    }
}

// ---------------- feat: acc1=A1@Wt^T, acc2=A2@Wt^T; write Xb pair + cheby G ----------------
__global__ __launch_bounds__(256) void k_mm_feat(const float* __restrict__ A1,
                                                 const float* __restrict__ A2,
                                                 const unsigned short* __restrict__ Wt,
                                                 unsigned short* __restrict__ G,
                                                 unsigned short* __restrict__ X1b,
                                                 unsigned short* __restrict__ X2b, int M) {
    __shared__ ushort8v AV1[512], AV2[512], BV[1024];
    unsigned short* Als1 = (unsigned short*)AV1;
    unsigned short* Als2 = (unsigned short*)AV2;
    unsigned short* Bls = (unsigned short*)BV;
    const int t = threadIdx.x, l = t & 63, w = t >> 6, lr = l & 15, lg = l >> 4;
    const int r0 = blockIdx.x * 64;
    f32x4 acc1[8], acc2[8];
#pragma unroll
    for (int ni = 0; ni < 8; ++ni) {
        acc1[ni] = (f32x4){0.f, 0.f, 0.f, 0.f};
        acc2[ni] = (f32x4){0.f, 0.f, 0.f, 0.f};
    }
    for (int k0 = 0; k0 < 128; k0 += 64) {
        mm_stage_A_f32(A1, 128, M, r0, k0, Als1, t);
        mm_stage_A_f32(A2, 128, M, r0, k0, Als2, t);
        mm_stage_B(Wt, 128, k0, Bls, t);
        __syncthreads();
        mm_tile_mfma(Als1, Bls, w, lr, lg, acc1);
        mm_tile_mfma(Als2, Bls, w, lr, lg, acc2);
        __syncthreads();
    }
#pragma unroll
    for (int ni = 0; ni < 8; ++ni) {
        int col = ni * 16 + lr;
#pragma unroll
        for (int rg = 0; rg < 4; ++rg) {
            int grow = r0 + w * 16 + lg * 4 + rg;
            if (grow < M) {
                float v1 = acc1[ni][rg], v2 = acc2[ni][rg];
                X1b[(size_t)grow * 128 + col] = bfr(v1);
                X2b[(size_t)grow * 128 + col] = bfr(v2);
                float x1 = tanhf(v1), x2 = tanhf(v2);
                ushort4v g4;
                g4.x = bfr(2.0f);
                g4.y = bfr(x1 + x2);
                g4.z = bfr((2.f * x1 * x1 - 1.f) + (2.f * x2 * x2 - 1.f));
                g4.w = bfr(x1 * (4.f * x1 * x1 - 3.f) + x2 * (4.f * x2 * x2 - 3.f));
                *(ushort4v*)&G[(size_t)grow * 512 + col * 4] = g4;
            }
        }
    }
}

// ---------------- mix: pre = Gb@Wt^T (K=512); F = sig(pre)*X1b + (1-sig)*X2b ----------------
__global__ __launch_bounds__(256) void k_mm_mix(const unsigned short* __restrict__ Gb,
                                                const unsigned short* __restrict__ Wt,
                                                const unsigned short* __restrict__ X1b,
                                                const unsigned short* __restrict__ X2b,
                                                unsigned short* __restrict__ F, int M) {
    __shared__ ushort8v AV[512], BV[1024];
    unsigned short* Als = (unsigned short*)AV;
    unsigned short* Bls = (unsigned short*)BV;
    const int t = threadIdx.x, l = t & 63, w = t >> 6, lr = l & 15, lg = l >> 4;
    const int r0 = blockIdx.x * 64;
    f32x4 acc[8];
#pragma unroll
    for (int ni = 0; ni < 8; ++ni) acc[ni] = (f32x4){0.f, 0.f, 0.f, 0.f};
    for (int k0 = 0; k0 < 512; k0 += 64) {
        mm_stage_A_bf(Gb, 512, M, r0, k0, Als, t);
        mm_stage_B(Wt, 512, k0, Bls, t);
        __syncthreads();
        mm_tile_mfma(Als, Bls, w, lr, lg, acc);
        __syncthreads();
    }
#pragma unroll
    for (int ni = 0; ni < 8; ++ni) {
        int col = ni * 16 + lr;
#pragma unroll
        for (int rg = 0; rg < 4; ++rg) {
            int grow = r0 + w * 16 + lg * 4 + rg;
            if (grow < M) {
                float g = sigf(acc[ni][rg]);
                float x1 = b2f(X1b[(size_t)grow * 128 + col]);
                float x2 = b2f(X2b[(size_t)grow * 128 + col]);
                F[(size_t)grow * 128 + col] = bfr(g * x1 + (1.f - g) * x2);
            }
        }
    }
}

// ---------------- final: acc = A0@B0^T + A1@B1^T; out[r] = dot(acc[r], FU)/128 ----------------
__device__ inline void mm_pair_accum(const unsigned short* A, const unsigned short* Bw, int M,
                                     int r0, int t, int w, int lr, int lg,
                                     unsigned short* Als, unsigned short* Bls, f32x4* acc) {
    for (int k0 = 0; k0 < 128; k0 += 64) {
        mm_stage_A_bf(A, 128, M, r0, k0, Als, t);
        mm_stage_B(Bw, 128, k0, Bls, t);
        __syncthreads();
        mm_tile_mfma(Als, Bls, w, lr, lg, acc);
        __syncthreads();
    }
}

__global__ __launch_bounds__(256) void k_mm_final(const unsigned short* __restrict__ A0,
                                                  const unsigned short* __restrict__ B0,
                                                  const unsigned short* __restrict__ A1,
                                                  const unsigned short* __restrict__ B1,
                                                  const float* __restrict__ FU,
                                                  float* __restrict__ out, int M) {
    __shared__ ushort8v AV[512], BV[1024];
    unsigned short* Als = (unsigned short*)AV;
    unsigned short* Bls = (unsigned short*)BV;
    const int t = threadIdx.x, l = t & 63, w = t >> 6, lr = l & 15, lg = l >> 4;
    const int r0 = blockIdx.x * 64;
    f32x4 acc[8];
#pragma unroll
    for (int ni = 0; ni < 8; ++ni) acc[ni] = (f32x4){0.f, 0.f, 0.f, 0.f};
    mm_pair_accum(A0, B0, M, r0, t, w, lr, lg, Als, Bls, acc);
    mm_pair_accum(A1, B1, M, r0, t, w, lr, lg, Als, Bls, acc);
    float fuv[8];
#pragma unroll
    for (int ni = 0; ni < 8; ++ni) fuv[ni] = FU[ni * 16 + lr];
#pragma unroll
    for (int rg = 0; rg < 4; ++rg) {
        float v = 0.f;
#pragma unroll
        for (int ni = 0; ni < 8; ++ni) v += acc[ni][rg] * fuv[ni];
        v += __shfl_xor(v, 1);
        v += __shfl_xor(v, 2);
        v += __shfl_xor(v, 4);
        v += __shfl_xor(v, 8);
        int grow = r0 + w * 16 + lg * 4 + rg;
        if (lr == 0 && grow < M) out[grow] = v * (1.f / 128.f);
    }
}

// =================== gconv: C += UI[M x K fp32] @ Bt[128 x KP bf16]^T, LDS-staged ===================
__global__ __launch_bounds__(256) void k_gconv2(const float* __restrict__ A,
                                                const unsigned short* __restrict__ Bt,
                                                float* __restrict__ C,
                                                int M, int K, int klen) {
    __shared__ ushort8v AV[1024], BV[1024];  // 128 rows x 64 bf16 each
    unsigned short* Als = (unsigned short*)AV;
    unsigned short* Bls = (unsigned short*)BV;
    const int t = threadIdx.x, l = t & 63, w = t >> 6, lr = l & 15, lg = l >> 4;
    const int r0 = blockIdx.x * 128;
    const int kbeg = blockIdx.y * klen;
    const int kend = min(K, kbeg + klen);
    f32x4 acc[2][8];
#pragma unroll
    for (int mi = 0; mi < 2; ++mi)
#pragma unroll
        for (int ni = 0; ni < 8; ++ni) acc[mi][ni] = (f32x4){0.f, 0.f, 0.f, 0.f};

    for (int k0 = kbeg; k0 < kend; k0 += 64) {
        // stage A: 128 x 64 fp32 -> bf16 (float2 grain; lda=K=8234 is even)
#pragma unroll
        for (int u = 0; u < 16; ++u) {
            int idx = u * 256 + t;
            int row = idx >> 5, c2 = idx & 31;
            int gr = r0 + row, gk = k0 + c2 * 2;
            float2 v = make_float2(0.f, 0.f);
            if (gr < M && gk < K) v = *(const float2*)(A + (size_t)gr * K + gk);
            unsigned int pk = (unsigned int)bfr(v.x) | ((unsigned int)bfr(v.y) << 16);
            *(unsigned int*)&Als[row * 64 + (((c2 >> 2) ^ (row & 7)) << 3) + ((c2 & 3) << 1)] = pk;
        }
        // stage B: 128 x 64 bf16 (Bt zero-padded to KP)
#pragma unroll
        for (int u = 0; u < 4; ++u) {
            int idx = u * 256 + t;
            int row = idx >> 3, c = idx & 7;
            int gk = k0 + c * 8;
            ushort8v v = (ushort8v){0, 0, 0, 0, 0, 0, 0, 0};
            if (gk < KP) v = *(const ushort8v*)(Bt + (size_t)row * KP + gk);
            *(ushort8v*)&Bls[row * 64 + ((c ^ (row & 7)) << 3)] = v;
        }
        __syncthreads();
#pragma unroll
        for (int s = 0; s < 2; ++s) {
            int ch = s * 4 + lg;
            short8v a0 = *(const short8v*)&Als[(w * 32 + lr) * 64 + ((ch ^ (lr & 7)) << 3)];
            short8v a1 = *(const short8v*)&Als[(w * 32 + 16 + lr) * 64 + ((ch ^ (lr & 7)) << 3)];
#pragma unroll
            for (int ni = 0; ni < 8; ++ni) {
                short8v b = *(const short8v*)&Bls[(ni * 16 + lr) * 64 + ((ch ^ (lr & 7)) << 3)];
                acc[0][ni] = __builtin_amdgcn_mfma_f32_16x16x32_bf16(a0, b, acc[0][ni], 0, 0, 0);
                acc[1][ni] = __builtin_amdgcn_mfma_f32_16x16x32_bf16(a1, b, acc[1][ni], 0, 0, 0);
            }
        }
        __syncthreads();
    }
#pragma unroll
    for (int mi = 0; mi < 2; ++mi) {
#pragma unroll
        for (int rg = 0; rg < 4; ++rg) {
            int grow = r0 + w * 32 + mi * 16 + lg * 4 + rg;
            if (grow < M) {
#pragma unroll
                for (int ni = 0; ni < 8; ++ni)
                    atomAddF(&C[(size_t)grow * 128 + ni * 16 + lr], acc[mi][ni][rg]);
            }
        }
    }
}

// =================== retained kernels ===================
// generic fp32 GEMM (hconv only): C[M x 128] += A[M x K] @ B[K x 128], atomic store
#define GEMM_BODY(K_)                                                     \
    {                                                                     \
        float a[4], b[8];                                                 \
        _Pragma("unroll") for (int r = 0; r < 4; r++) a[r] = As[ty + 16 * r][K_]; \
        _Pragma("unroll") for (int c = 0; c < 8; c++) b[c] = Bs[K_][tx + 16 * c]; \
        _Pragma("unroll") for (int r = 0; r < 4; r++)                     \
            _Pragma("unroll") for (int c = 0; c < 8; c++)                 \
                acc[r][c] += a[r] * b[c];                                 \
    }

__global__ __launch_bounds__(256) void k_gemm(const float* __restrict__ A, int lda,
                                              const float* __restrict__ B,
                                              float* __restrict__ C,
                                              int M, int K, float alpha, int klen) {
    __shared__ float As[64][33];
    __shared__ float Bs[32][128];
    const int t = threadIdx.x;
    const int tx = t & 15, ty = t >> 4;
    const int i0 = blockIdx.x * 64;
    const int kbeg = blockIdx.y * klen;
    const int kend = min(K, kbeg + klen);
    float acc[4][8];
#pragma unroll
    for (int r = 0; r < 4; r++)
#pragma unroll
        for (int c = 0; c < 8; c++) acc[r][c] = 0.f;

    for (int k0 = kbeg; k0 < kend; k0 += 32) {
#pragma unroll
        for (int q = 0; q < 2; q++) {
            int idx = t + q * 256;
            int row = idx >> 3;
            int col = (idx & 7) * 4;
            int gi = i0 + row;
#pragma unroll
            for (int u = 0; u < 4; u++) {
                int gk = k0 + col + u;
                As[row][col + u] = (gi < M && gk < kend) ? A[(size_t)gi * lda + gk] : 0.f;
            }
        }
#pragma unroll
        for (int q = 0; q < 4; q++) {
            int idx = t + q * 256;
            int row = idx >> 5;
            int col4 = (idx & 31) * 4;
            int gk = k0 + row;
            float4 v = make_float4(0.f, 0.f, 0.f, 0.f);
            if (gk < kend) v = *reinterpret_cast<const float4*>(B + (size_t)gk * 128 + col4);
            *reinterpret_cast<float4*>(&Bs[row][col4]) = v;
        }
        __syncthreads();
        int klim = min(32, kend - k0);
        if (klim == 32) {
#pragma unroll
            for (int k = 0; k < 32; k++) GEMM_BODY(k)
        } else {
            for (int k = 0; k < klim; k++) GEMM_BODY(k)
        }
        __syncthreads();
    }
#pragma unroll
    for (int r = 0; r < 4; r++) {
        int gi = i0 + ty + 16 * r;
        if (gi < M) {
#pragma unroll
            for (int c = 0; c < 8; c++)
                atomAddF(&C[(size_t)gi * 128 + tx + 16 * c], alpha * acc[r][c]);
        }
    }
}

__global__ void k_small_pu(const float* __restrict__ PUm, const float* __restrict__ X,
                           float* __restrict__ T, int Kn) {
    int i = blockIdx.x;
    int klen = (Kn + gridDim.y - 1) / gridDim.y;
    int kbeg = blockIdx.y * klen;
    int kend = min(Kn, kbeg + klen);
    int t = threadIdx.x;
    int d = t & 127, half = t >> 7;
    float acc = 0.f;
    for (int k = kbeg + half; k < kend; k += 2)
        acc += PUm[(size_t)i * Kn + k] * X[(size_t)k * 128 + d];
    atomAddF(&T[i * 128 + d], acc);
}

__global__ void k_acc3norm(const float* __restrict__ a, const float* __restrict__ b,
                           const float* __restrict__ c, float* __restrict__ out) {
    __shared__ float red[128];
    size_t i = blockIdx.x;
    int d = threadIdx.x;
    float v = (a[i * 128 + d] + b[i * 128 + d] + c[i * 128 + d]) * (1.f / 3.f);
    red[d] = v * v;
    __syncthreads();
    for (int s = 64; s > 0; s >>= 1) {
        if (d < s) red[d] += red[d + s];
        __syncthreads();
    }
    float inv = 1.f / fmaxf(sqrtf(red[0]), 1e-12f);
    out[i * 128 + d] = v * inv;
}

__global__ void k_prep(const float* __restrict__ X, const float* __restrict__ Yadd,
                       float scale, unsigned short* __restrict__ Zb) {
    __shared__ float red[128];
    size_t i = blockIdx.x;
    int d = threadIdx.x;
    float v = X[i * 128 + d];
    if (Yadd) v += Yadd[i * 128 + d];
    red[d] = v * v;
    __syncthreads();
    for (int s = 64; s > 0; s >>= 1) {
        if (d < s) red[d] += red[d + s];
        __syncthreads();
    }
    float inv = scale / fmaxf(sqrtf(red[0]), 1e-12f);
    Zb[i * 128 + d] = bfr(v * inv);
}

// fused InfoNCE tile pass (bf16 MFMA) — unchanged from round 2 (verified, 0 conflicts)
__global__ __launch_bounds__(256) void k_rowcol_mfma(
    const unsigned short* __restrict__ Za, int n1,
    const unsigned short* __restrict__ Zb, int n2,
    float* __restrict__ rowsum, float* __restrict__ colsum, float* __restrict__ diagsum) {
    __shared__ ushort8v As[2048];
    __shared__ ushort8v Bs[2048];
    const int t = threadIdx.x;
    const int i0 = blockIdx.x * 128, j0 = blockIdx.y * 128;
#pragma unroll
    for (int u = 0; u < 8; ++u) {
        int g = t + u * 256;
        int row = g >> 4, c = g & 15;
        int sw = (row << 4) | (c ^ (row & 15));
        ushort8v va = (ushort8v){0, 0, 0, 0, 0, 0, 0, 0};
        ushort8v vb = va;
        if (i0 + row < n1) va = *(const ushort8v*)(Za + ((size_t)(i0 + row) << 7) + c * 8);
        if (j0 + row < n2) vb = *(const ushort8v*)(Zb + ((size_t)(j0 + row) << 7) + c * 8);
        As[sw] = va;
        Bs[sw] = vb;
    }
    __syncthreads();
    const int l = t & 63, w = t >> 6;
    const int wy = w >> 1, wx = w & 1;
    const int lr = l & 15, lg = l >> 4;
    f32x4 acc[4][4];
#pragma unroll
    for (int mi = 0; mi < 4; ++mi)
#pragma unroll
        for (int ni = 0; ni < 4; ++ni) acc[mi][ni] = (f32x4){0.f, 0.f, 0.f, 0.f};

#pragma unroll
    for (int ks = 0; ks < 4; ++ks) {
        short8v a[4], b[4];
        int c = ks * 4 + lg;
#pragma unroll
        for (int mi = 0; mi < 4; ++mi) {
            int r = wy * 64 + mi * 16 + lr;
            a[mi] = __builtin_bit_cast(short8v, As[(r << 4) | (c ^ (r & 15))]);
            int r2 = wx * 64 + mi * 16 + lr;
            b[mi] = __builtin_bit_cast(short8v, Bs[(r2 << 4) | (c ^ (r2 & 15))]);
        }
#pragma unroll
        for (int mi = 0; mi < 4; ++mi)
#pragma unroll
            for (int ni = 0; ni < 4; ++ni)
                acc[mi][ni] = __builtin_amdgcn_mfma_f32_16x16x32_bf16(a[mi], b[ni], acc[mi][ni], 0, 0, 0);
    }
    float colp[4] = {0.f, 0.f, 0.f, 0.f};
    float dsum = 0.f;
#pragma unroll
    for (int mi = 0; mi < 4; ++mi) {
#pragma unroll
        for (int rg = 0; rg < 4; ++rg) {
            int grow = i0 + wy * 64 + mi * 16 + lg * 4 + rg;
            float rowp = 0.f;
#pragma unroll
            for (int ni = 0; ni < 4; ++ni) {
                int gcol = j0 + wx * 64 + ni * 16 + lr;
                float v = acc[mi][ni][rg];
                bool ok = (grow < n1) && (gcol < n2);
                float e = ok ? __expf(v) : 0.f;
                rowp += e;
                colp[ni] += e;
                if (ok && grow == gcol) dsum += v;
            }
            rowp += __shfl_xor(rowp, 1);
            rowp += __shfl_xor(rowp, 2);
            rowp += __shfl_xor(rowp, 4);
            rowp += __shfl_xor(rowp, 8);
            if (lr == 0 && grow < n1) atomAddF(&rowsum[grow], rowp);
        }
    }
#pragma unroll
    for (int ni = 0; ni < 4; ++ni) {
        float cp = colp[ni];
        cp += __shfl_xor(cp, 16);
        cp += __shfl_xor(cp, 32);
        int gcol = j0 + wx * 64 + ni * 16 + lr;
        if (lg == 0 && gcol < n2) atomAddF(&colsum[gcol], cp);
    }
    if (blockIdx.x == blockIdx.y) {
        dsum += __shfl_xor(dsum, 1);
        dsum += __shfl_xor(dsum, 2);
        dsum += __shfl_xor(dsum, 4);
        dsum += __shfl_xor(dsum, 8);
        dsum += __shfl_xor(dsum, 16);
        dsum += __shfl_xor(dsum, 32);
        if (l == 0) atomAddF(diagsum, dsum);
    }
}

__global__ __launch_bounds__(256) void k_tconv(const float* __restrict__ B,
                                               unsigned short* __restrict__ Bt, int K) {
    __shared__ float tile[32][33];
    int tx = threadIdx.x & 31, ty = threadIdx.x >> 5;
    int k0 = blockIdx.x * 32, c0 = blockIdx.y * 32;
#pragma unroll
    for (int q = 0; q < 4; ++q) {
        int k = k0 + ty + q * 8;
        tile[ty + q * 8][tx] = (k < K) ? B[(size_t)k * 128 + c0 + tx] : 0.f;
    }
    __syncthreads();
#pragma unroll
    for (int q = 0; q < 4; ++q) {
        int c = c0 + ty + q * 8;
        Bt[(size_t)c * KP + k0 + tx] = bfr(tile[tx][ty + q * 8]);
    }
}

__global__ void k_nce_reduce(const float* __restrict__ rs, const float* __restrict__ cs,
                             const float* __restrict__ diag, int n, float* __restrict__ loss) {
    __shared__ float red[256];
    int t = threadIdx.x;
    float s = 0.f;
    for (int i = blockIdx.x * 256 + t; i < n; i += gridDim.x * 256)
        s += logf(rs[i]) + logf(cs[i]);
    red[t] = s;
    __syncthreads();
    for (int st = 128; st > 0; st >>= 1) {
        if (t < st) red[t] += red[t + st];
        __syncthreads();
    }
    if (t == 0) {
        float v = 0.5f * red[0] / (float)n;
        if (blockIdx.x == 0) v -= diag[0] / (float)n;
        atomAddF(loss, v);
    }
}

__global__ void k_ssl(const float* __restrict__ UE, const float* __restrict__ HGU,
                      float* __restrict__ loss) {
    __shared__ float A[NUC][128], B[NUC][128];
    __shared__ float sim[NUC][NUC];
    __shared__ float invA[NUC], invB[NUC];
    __shared__ float pr[64];
    int t = threadIdx.x;
    for (int idx = t; idx < NUC * 128; idx += 256) {
        A[idx >> 7][idx & 127] = UE[idx];
        B[idx >> 7][idx & 127] = HGU[9 * 128 + idx];
    }
    __syncthreads();
    if (t < 2 * NUC) {
        int i = (t < NUC) ? t : t - NUC;
        float s = 0.f;
        if (t < NUC) {
            for (int d = 0; d < 128; d++) { float v = A[i][d]; s += v * v; }
            invA[i] = 1.f / fmaxf(sqrtf(s), 1e-12f);
        } else {
            for (int d = 0; d < 128; d++) { float v = B[i][d]; s += v * v; }
            invB[i] = 1.f / fmaxf(sqrtf(s), 1e-12f);
        }
    }
    __syncthreads();
    for (int idx = t; idx < NUC * NUC; idx += 256) {
        int i = idx / NUC, j = idx % NUC;
        float s = 0.f;
        for (int d = 0; d < 128; d++) s += A[i][d] * B[j][d];
        sim[i][j] = s * invA[i] * invB[j] * 5.0f;
    }
    __syncthreads();
    float part = 0.f;
    if (t < NUC) {
        float rsu = 0.f, csu = 0.f;
        for (int j = 0; j < NUC; j++) {
            rsu += __expf(sim[t][j]);
            csu += __expf(sim[j][t]);
        }
        part = 0.5f * (logf(rsu) + logf(csu)) - sim[t][t];
    }
    if (t < 64) pr[t] = (t < NUC) ? part : 0.f;
    __syncthreads();
    if (t == 0) {
        float s = 0.f;
        for (int i = 0; i < NUC; i++) s += pr[i];
        atomAddF(loss, s / (float)NUC);
    }
}

__global__ void k_finalu(const float* __restrict__ UE, const float* __restrict__ HGU,
                         const int* __restrict__ uui, const int* __restrict__ ucol,
                         float* __restrict__ fu) {
    int d = threadIdx.x;
    fu[d] = UE[(size_t)(*uui) * 128 + d] + HGU[(*ucol) * 128 + d];
}

__global__ void k_predloss(const float* __restrict__ ov, const int* __restrict__ tgt,
                           float* __restrict__ loss) {
    __shared__ float red[256];
    int t = threadIdx.x;
    float m = -1e30f;
    for (int i = t; i < P; i += 256) m = fmaxf(m, ov[i]);
    red[t] = m;
    __syncthreads();
    for (int s = 128; s > 0; s >>= 1) {
        if (t < s) red[t] = fmaxf(red[t], red[t + s]);
        __syncthreads();
    }
    float mg = red[0];
    __syncthreads();
    float ssum = 0.f;
    for (int i = t; i < P; i += 256) ssum += __expf(ov[i] - mg);
    red[t] = ssum;
    __syncthreads();
    for (int s = 128; s > 0; s >>= 1) {
        if (t < s) red[t] += red[t + s];
        __syncthreads();
    }
    if (t == 0) {
        float lse = mg + logf(red[0]);
        atomAddF(loss, lse - ov[*tgt]);
    }
}

__global__ void k_writeloss(const float* __restrict__ sc, float* __restrict__ out) {
    out[0] = sc[0];
}

extern "C" void kernel_launch(void* const* d_in, const int* in_sizes, int n_in,
                              void* d_out, int out_size, void* d_ws, size_t ws_size,
                              hipStream_t stream) {
    const float* poi_w  = (const float*)d_in[0];
    const float* ui_w   = (const float*)d_in[1];
    const float* Wc     = (const float*)d_in[2];
    const float* bc     = (const float*)d_in[3];
    const float* WU     = (const float*)d_in[4];
    const float* bU     = (const float*)d_in[5];
    const float* cr     = (const float*)d_in[6];
    const float* ci     = (const float*)d_in[7];
    const float* HGpu   = (const float*)d_in[8];
    const float* HGup   = (const float*)d_in[9];
    const float* UI     = (const float*)d_in[10];
    const float* noise1 = (const float*)d_in[11];
    const float* noise2 = (const float*)d_in[12];
    const int* target   = (const int*)d_in[13];
    const int* ucol     = (const int*)d_in[14];
    const int* uui      = (const int*)d_in[15];
    float* out = (float*)d_out;

    float* ws = (float*)d_ws;
    size_t o = 0;
    auto alloc = [&](size_t n) { float* p = ws + o; o += (n + 3) & ~(size_t)3; return p; };
    float* H   = alloc((size_t)P * D);
    float* UE  = alloc((size_t)PU * D);
    float* B1  = alloc((size_t)PU * D);
    float* B2  = alloc((size_t)PU * D);
    float* B3  = alloc((size_t)PU * D);
    float* B4  = alloc((size_t)PU * D);
    float* TS  = alloc(NHE * D);
    float* HGU = alloc(NHE * D);
    float* RS  = alloc(8240);
    float* CS  = alloc(8240);
    float* SC  = alloc(16);
    float* FU  = alloc(D);
    unsigned short* ZA  = (unsigned short*)alloc((size_t)PU * D / 2);
    unsigned short* ZB  = (unsigned short*)alloc((size_t)PU * D / 2);
    unsigned short* ZC  = (unsigned short*)alloc((size_t)PU * D / 2);
    unsigned short* BT  = (unsigned short*)alloc((size_t)D * KP / 2);
    unsigned short* CMt = (unsigned short*)alloc(D * D / 2);
    unsigned short* SMt = (unsigned short*)alloc(D * D / 2);
    unsigned short* WRt = (unsigned short*)alloc(D * 512 / 2);
    unsigned short* WIt = (unsigned short*)alloc(D * 512 / 2);
    unsigned short* WCt = (unsigned short*)alloc(D * D / 2);
    unsigned short* WUt = (unsigned short*)alloc(D * D / 2);
    unsigned short* Gb  = (unsigned short*)alloc((size_t)P * 512 / 2);
    if (o * sizeof(float) > ws_size) return;
    // aliases (lifetimes verified: ZA/ZB/ZC/BT all dead before the KAN phase)
    unsigned short* X1b = ZB;
    unsigned short* X2b = BT;
    unsigned short* FRb = ZA;
    unsigned short* FIb = ZC;

    auto Z = [&](float* p, size_t n) { hipMemsetAsync(p, 0, n * sizeof(float), stream); };
    auto GEMM = [&](const float* A, int lda, const float* B, float* C, int M, int K,
                    int ysplit, float alpha) {
        int klen = (K + ysplit - 1) / ysplit;
        dim3 g((M + 63) / 64, ysplit);
        k_gemm<<<g, 256, 0, stream>>>(A, lda, B, C, M, K, alpha, klen);
    };
    auto GCONV = [&](const float* Xin, float* Cout) {
        k_tconv<<<dim3(KP / 32, 4), 256, 0, stream>>>(Xin, BT, PU);
        const int ksplit = 16;
        const int klen = 544;  // ceil(PU/16) rounded up to 64; 16*544 >= PU
        k_gconv2<<<dim3((PU + 127) / 128, ksplit), 256, 0, stream>>>(UI, BT, Cout, PU, PU, klen);
    };
    auto NCE = [&](const unsigned short* z1, int n1, const unsigned short* z2, int n2,
                   float* dslot) {
        Z(RS, n1); Z(CS, n2);
        dim3 g((n1 + 127) / 128, (n2 + 127) / 128);
        k_rowcol_mfma<<<g, 256, 0, stream>>>(z1, n1, z2, n2, RS, CS, dslot);
        k_nce_reduce<<<32, 256, 0, stream>>>(RS, CS, dslot, n1, SC);
    };

    Z(SC, 16);
    k_tables_bf<<<64, 256, 0, stream>>>(CMt, SMt);
    k_reshape_bf<<<256, 256, 0, stream>>>(cr, ci, WRt, WIt);
    k_convW<<<64, 256, 0, stream>>>(Wc, WCt);
    k_convW<<<64, 256, 0, stream>>>(WU, WUt);

    // ---- gates (fused GEMM + sigmoid-gate epilogue) ----
    k_mm_gate<<<(P + 63) / 64, 256, 0, stream>>>(poi_w, WCt, bc, B1, P);    // col_gate -> B1
    k_mm_gate<<<(PU + 63) / 64, 256, 0, stream>>>(ui_w, WUt, bU, B3, PU);   // U_gate  -> B3

    // ---- hconv -> H ----
    Z(TS, NHE * D);
    k_small_pu<<<dim3(NHE, 16), 256, 0, stream>>>(HGpu, B1, TS, P);
    Z(B2, (size_t)P * D);
    GEMM(HGup, NHE, TS, B2, P, NHE, 1, 1.f);                                // e1 -> B2
    Z(TS, NHE * D);
    k_small_pu<<<dim3(NHE, 16), 256, 0, stream>>>(HGpu, B2, TS, P);
    Z(B4, (size_t)P * D);
    GEMM(HGup, NHE, TS, B4, P, NHE, 1, 1.f);                                // e2 -> B4
    k_acc3norm<<<P, 128, 0, stream>>>(B1, B2, B4, H);

    // ---- hg_users ----
    Z(HGU, NHE * D);
    k_small_pu<<<dim3(NHE, 16), 256, 0, stream>>>(HGpu, H, HGU, P);

    // ---- level_loss = info_nce(H, H + noise1) ----
    k_prep<<<P, 128, 0, stream>>>(H, nullptr, 5.f, ZA);   // ZA reused for ssl_p
    k_prep<<<P, 128, 0, stream>>>(H, noise1, 1.f, ZB);
    NCE(ZA, P, ZB, P, SC + 1);

    // ---- gconv -> UE ----
    Z(B2, (size_t)PU * D);
    GCONV(B3, B2);                                                          // e1 -> B2
    Z(B4, (size_t)PU * D);
    GCONV(B2, B4);                                                          // e2 -> B4
    k_acc3norm<<<PU, 128, 0, stream>>>(B3, B2, B4, UE);

    // ---- level_loss1 = info_nce(UE, UE + noise2) ----
    k_prep<<<PU, 128, 0, stream>>>(UE, nullptr, 5.f, ZC);
    k_prep<<<PU, 128, 0, stream>>>(UE, noise2, 1.f, ZB);
    NCE(ZC, PU, ZB, PU, SC + 2);

    // ---- ssl_p = info_nce(H, poi_e) ----
    const float* poi_e = UE + (size_t)NUC * D;
    k_prep<<<P, 128, 0, stream>>>(poi_e, nullptr, 1.f, ZB);
    NCE(ZA, P, ZB, P, SC + 3);

    // ---- ssl (tiny) ----
    k_ssl<<<1, 256, 0, stream>>>(UE, HGU, SC);

    // ---- gated_kan (fused MFMA pipeline; ZA/ZB/ZC/BT now dead -> aliased) ----
    k_mm_feat<<<P / 64, 256, 0, stream>>>(H, poi_e, CMt, Gb, X1b, X2b, P);  // real part
    k_mm_mix<<<P / 64, 256, 0, stream>>>(Gb, WRt, X1b, X2b, FRb, P);        // fr (bf16)
    k_mm_feat<<<P / 64, 256, 0, stream>>>(H, poi_e, SMt, Gb, X1b, X2b, P);  // imag part
    k_mm_mix<<<P / 64, 256, 0, stream>>>(Gb, WIt, X1b, X2b, FIb, P);        // fi (bf16)

    // ---- final output + pred_loss ----
    k_finalu<<<1, 128, 0, stream>>>(UE, HGU, uui, ucol, FU);
    k_mm_final<<<P / 64, 256, 0, stream>>>(FRb, CMt, FIb, SMt, FU, out + 1, P);
    k_predloss<<<1, 256, 0, stream>>>(out + 1, target, SC);
    k_writeloss<<<1, 1, 0, stream>>>(SC, out);
}